// Round 3
// baseline (232.089 us; speedup 1.0000x reference)
//
#include <hip/hip_runtime.h>

#define T_TOK  16384
#define IN_F   1024
#define OUT_F  1024
#define NE     8

typedef __bf16 bf16;
typedef bf16  bf16x4 __attribute__((ext_vector_type(4)));
typedef bf16  bf16x8 __attribute__((ext_vector_type(8)));
typedef float f32x4  __attribute__((ext_vector_type(4)));

// ---------------------------------------------------------------------------
// Pass 1: fp32 -> bf16 convert of x and W into workspace.
// ---------------------------------------------------------------------------
#define CVT_THREADS 256
#define NX_CHUNKS (T_TOK * IN_F / 4)
#define NW_CHUNKS (NE * OUT_F * IN_F / 4)
#define NTOT_CHUNKS (NX_CHUNKS + NW_CHUNKS)

__global__ __launch_bounds__(CVT_THREADS)
void cvt_f32_to_bf16(const float* __restrict__ x, const float* __restrict__ w,
                     bf16* __restrict__ xb, bf16* __restrict__ wb)
{
    for (int i = blockIdx.x * CVT_THREADS + threadIdx.x; i < NTOT_CHUNKS;
         i += gridDim.x * CVT_THREADS) {
        const bool isx = (i < NX_CHUNKS);
        const int  j   = isx ? i : i - NX_CHUNKS;
        f32x4 v = isx ? ((const f32x4*)x)[j] : ((const f32x4*)w)[j];
        bf16x4 h;
        #pragma unroll
        for (int k = 0; k < 4; ++k) h[k] = (bf16)v[k];
        if (isx) ((bf16x4*)xb)[j] = h;
        else     ((bf16x4*)wb)[j] = h;
    }
}

// ---------------------------------------------------------------------------
// Pass 2: grouped GEMM, 256x256 tile, BK=64, 8 waves (2M x 4N), 2-phase:
// gld_lds prefetch into alternate LDS buffer BEFORE compute, ONE barrier
// per K-step (T3-minimum recipe; m248 2ph ref = 666 TF at this shape).
// ---------------------------------------------------------------------------
#define BM 256
#define BN 256
#define BK 64
#define GTHREADS 512
#define ROW_SLOTS 72    // max sum ceil(len_e/256) = 64 + 8

__device__ __forceinline__ void gld_lds16(const bf16* g, bf16* l) {
    __builtin_amdgcn_global_load_lds(
        (const __attribute__((address_space(1))) void*)g,
        (__attribute__((address_space(3))) void*)l,
        16, 0, 0);
}

__global__ __launch_bounds__(GTHREADS)
void grouped_gemm_bf16_256(const bf16* __restrict__ xb,
                           const bf16* __restrict__ wb,
                           const int*  __restrict__ seg_lens,
                           float* __restrict__ out)
{
    __shared__ __align__(16) bf16 As[2][BM * BK];   // 2 x 32 KiB
    __shared__ __align__(16) bf16 Bs[2][BN * BK];   // 2 x 32 KiB  (128 KiB total)

    const int m    = blockIdx.y;
    const int col0 = blockIdx.x * BN;

    // ---- slot m -> (expert, row0, valid rows); 256-row granularity ----
    int e_sel = -1, row0 = 0, rows = 0;
    {
        int start = 0, acct = 0;
        #pragma unroll
        for (int e = 0; e < NE; ++e) {
            int len = seg_lens[e];
            int nt  = (len + BM - 1) >> 8;
            if (e_sel < 0 && m >= acct && m < acct + nt) {
                e_sel = e;
                row0  = start + (m - acct) * BM;
                int rem = start + len - row0;
                rows = rem < BM ? rem : BM;
            }
            acct  += nt;
            start += len;
        }
    }
    if (e_sel < 0) return;   // surplus slot, uniform exit before any barrier

    const int tid  = threadIdx.x;
    const int lane = tid & 63;
    const int wave = tid >> 6;
    const int wr   = wave >> 2;          // 0..1 : 128-row half
    const int wc   = wave & 3;           // 0..3 : 64-col quarter
    const int quad = lane >> 4;
    const int l16  = lane & 15;

    const bf16* wbase = wb + ((size_t)e_sel * OUT_F + (size_t)col0) * IN_F;

    // ---- staging geometry ----
    // Tile = 256 rows x 64 bf16 (128 B/row) = 32 KiB = 32 wave-issues of 1 KiB.
    // Wave w owns issues q = w*4+i (rows q*8 .. q*8+7).
    // lane l: row-in-issue = l>>3, k-elem = (l&7)*8.  LDS dest is wave-uniform
    // (q*1024 bytes); HW scatters lane*16B, matching row-major [256][64].
    const int rq = lane >> 3;
    const int ke = (lane & 7) * 8;
    const bf16* ga[4];
    const bf16* gb[4];
    #pragma unroll
    for (int i = 0; i < 4; ++i) {
        int q  = wave * 4 + i;
        int ra = row0 + q * 8 + rq;
        if (ra > T_TOK - 1) ra = T_TOK - 1;   // clamp partial last tile
        ga[i] = xb + (size_t)ra * IN_F + ke;
        gb[i] = wbase + (size_t)(q * 8 + rq) * IN_F + ke;
    }
    const int q0 = wave * 4;

    f32x4 acc[8][4] = {};

    // ---- prologue: stage K-tile 0 into buffer 0 ----
    #pragma unroll
    for (int i = 0; i < 4; ++i) {
        gld_lds16(ga[i], &As[0][(q0 + i) * 512]);
        gld_lds16(gb[i], &Bs[0][(q0 + i) * 512]);
    }
    __syncthreads();   // drains vmcnt(0): tile 0 resident

    int cur = 0;
    for (int ks = 0; ks < IN_F / BK; ++ks) {
        const int kn = (ks + 1) * BK;
        if (kn < IN_F) {     // issue NEXT tile into alternate buffer first
            #pragma unroll
            for (int i = 0; i < 4; ++i) {
                gld_lds16(ga[i] + kn, &As[cur ^ 1][(q0 + i) * 512]);
                gld_lds16(gb[i] + kn, &Bs[cur ^ 1][(q0 + i) * 512]);
            }
        }

        // ---- compute on current buffer: 2 x K=32 sub-steps, 64 MFMA/wave ----
        #pragma unroll
        for (int kk = 0; kk < 2; ++kk) {
            bf16x8 af[8], bfr[4];
            #pragma unroll
            for (int t = 0; t < 8; ++t)
                af[t] = *(const bf16x8*)(
                    &As[cur][(wr * 128 + t * 16 + l16) * BK + kk * 32 + quad * 8]);
            #pragma unroll
            for (int u = 0; u < 4; ++u)
                bfr[u] = *(const bf16x8*)(
                    &Bs[cur][(wc * 64 + u * 16 + l16) * BK + kk * 32 + quad * 8]);
            #pragma unroll
            for (int t = 0; t < 8; ++t)
                #pragma unroll
                for (int u = 0; u < 4; ++u)
                    acc[t][u] = __builtin_amdgcn_mfma_f32_16x16x32_bf16(
                        af[t], bfr[u], acc[t][u], 0, 0, 0);
        }

        __syncthreads();   // one barrier/K-step: drains next-tile vmcnt + reads
        cur ^= 1;
    }

    // ---- epilogue: C/D layout col=lane&15, row=quad*4+reg (m89/m91) ----
    #pragma unroll
    for (int t = 0; t < 8; ++t) {
        #pragma unroll
        for (int r = 0; r < 4; ++r) {
            int row = wr * 128 + t * 16 + quad * 4 + r;
            if (row < rows) {
                size_t ob = (size_t)(row0 + row) * OUT_F + col0 + wc * 64;
                #pragma unroll
                for (int u = 0; u < 4; ++u)
                    out[ob + u * 16 + l16] = acc[t][u][r];
            }
        }
    }
}

// ---------------------------------------------------------------------------
// Fallback (ws too small): round-0 kernel — fp32 loads, in-loop cvt.
// ---------------------------------------------------------------------------
#define FBM 128
#define FBK 32
#define FTHREADS 256
#define FROW_SLOTS 136

__global__ __launch_bounds__(FTHREADS)
void grouped_gemm_f32io_bf16(const float* __restrict__ x,
                             const float* __restrict__ wgt,
                             const int*  __restrict__ seg_lens,
                             float* __restrict__ out)
{
    __shared__ __align__(16) bf16 Asf[FBM * FBK];
    __shared__ __align__(16) bf16 Bsf[FBM * FBK];

    const int m    = blockIdx.y;
    const int col0 = blockIdx.x * FBM;

    int e_sel = -1, row0 = 0, rows = 0;
    {
        int start = 0, acct = 0;
        #pragma unroll
        for (int e = 0; e < NE; ++e) {
            int len = seg_lens[e];
            int nt  = (len + FBM - 1) >> 7;
            if (e_sel < 0 && m >= acct && m < acct + nt) {
                e_sel = e;
                row0  = start + (m - acct) * FBM;
                int rem = start + len - row0;
                rows = rem < FBM ? rem : FBM;
            }
            acct  += nt;
            start += len;
        }
    }
    if (e_sel < 0) return;

    const int tid  = threadIdx.x;
    const int lane = tid & 63;
    const int wave = tid >> 6;
    const int wm   = (wave >> 1) * 64;
    const int wn   = (wave & 1) * 64;
    const int quad = lane >> 4;
    const int l16  = lane & 15;

    const float* wbase = wgt + ((size_t)e_sel * OUT_F + (size_t)col0) * IN_F;

    f32x4 acc[4][4] = {};

    for (int k0 = 0; k0 < IN_F; k0 += FBK) {
        f32x4 a_st[4], b_st[4];
        #pragma unroll
        for (int t = 0; t < 4; ++t) {
            int c  = t * FTHREADS + tid;
            int rg = row0 + (c >> 3);
            if (rg > T_TOK - 1) rg = T_TOK - 1;
            a_st[t] = *(const f32x4*)(x + (size_t)rg * IN_F + k0 + (c & 7) * 4);
            b_st[t] = *(const f32x4*)(wbase + (size_t)(c >> 3) * IN_F + k0 + (c & 7) * 4);
        }

        __syncthreads();

        #pragma unroll
        for (int t = 0; t < 4; ++t) {
            int c = t * FTHREADS + tid;
            bf16x4 ha, hb;
            #pragma unroll
            for (int j = 0; j < 4; ++j) { ha[j] = (bf16)a_st[t][j]; hb[j] = (bf16)b_st[t][j]; }
            *(bf16x4*)(&Asf[(c >> 3) * FBK + (c & 7) * 4]) = ha;
            *(bf16x4*)(&Bsf[(c >> 3) * FBK + (c & 7) * 4]) = hb;
        }
        __syncthreads();

        bf16x8 af[4], bfr[4];
        #pragma unroll
        for (int t = 0; t < 4; ++t)
            af[t] = *(const bf16x8*)(&Asf[(wm + t * 16 + l16) * FBK + quad * 8]);
        #pragma unroll
        for (int u = 0; u < 4; ++u)
            bfr[u] = *(const bf16x8*)(&Bsf[(wn + u * 16 + l16) * FBK + quad * 8]);

        #pragma unroll
        for (int t = 0; t < 4; ++t)
            #pragma unroll
            for (int u = 0; u < 4; ++u)
                acc[t][u] = __builtin_amdgcn_mfma_f32_16x16x32_bf16(
                    af[t], bfr[u], acc[t][u], 0, 0, 0);
    }

    #pragma unroll
    for (int t = 0; t < 4; ++t) {
        #pragma unroll
        for (int r = 0; r < 4; ++r) {
            int row = wm + t * 16 + quad * 4 + r;
            if (row < rows) {
                size_t ob = (size_t)(row0 + row) * OUT_F + col0;
                #pragma unroll
                for (int u = 0; u < 4; ++u)
                    out[ob + wn + u * 16 + l16] = acc[t][u][r];
            }
        }
    }
}

extern "C" void kernel_launch(void* const* d_in, const int* in_sizes, int n_in,
                              void* d_out, int out_size, void* d_ws, size_t ws_size,
                              hipStream_t stream) {
    const float* x   = (const float*)d_in[0];
    const float* wgt = (const float*)d_in[1];
    const int*   seg = (const int*)d_in[2];
    float* out = (float*)d_out;

    const size_t xbytes = (size_t)T_TOK * IN_F * sizeof(bf16);       // 33.55 MB
    const size_t wbytes = (size_t)NE * OUT_F * IN_F * sizeof(bf16);  // 16.78 MB

    if (ws_size >= xbytes + wbytes) {
        bf16* xb = (bf16*)d_ws;
        bf16* wb = (bf16*)((char*)d_ws + xbytes);
        cvt_f32_to_bf16<<<dim3(2048, 1, 1), dim3(CVT_THREADS, 1, 1), 0, stream>>>(
            x, wgt, xb, wb);
        grouped_gemm_bf16_256<<<dim3(OUT_F / BN, ROW_SLOTS, 1),
                                dim3(GTHREADS, 1, 1), 0, stream>>>(xb, wb, seg, out);
    } else {
        grouped_gemm_f32io_bf16<<<dim3(OUT_F / FBM, FROW_SLOTS, 1),
                                  dim3(FTHREADS, 1, 1), 0, stream>>>(x, wgt, seg, out);
    }
}